// Round 1
// baseline (821.553 us; speedup 1.0000x reference)
//
#include <hip/hip_runtime.h>

#define DEVI __device__ __forceinline__

namespace {

constexpr int Nn = 50000;   // nodes
constexpr int Ne = 800000;  // edges
constexpr int Fd = 128;     // feature dim
constexpr int Hd = 256;     // hidden
constexpr int Cd = 40;      // classes

typedef __attribute__((ext_vector_type(8))) short s16x8;   // 8 bf16 (4 VGPR) MFMA frag
typedef __attribute__((ext_vector_type(4))) float f32x4;

DEVI unsigned short f2bf(float f) {
  unsigned int u = __builtin_bit_cast(unsigned int, f);
  u += 0x7fffu + ((u >> 16) & 1u);   // RNE
  return (unsigned short)(u >> 16);
}
DEVI float bf2f(unsigned short s) {
  return __builtin_bit_cast(float, ((unsigned int)s) << 16);
}

// ---------------- CSR build ----------------
__global__ void k_zero(int* cnt) {
  int i = blockIdx.x * 256 + threadIdx.x;
  if (i < Nn) cnt[i] = 0;
}

__global__ void k_count(const int* __restrict__ dst, int* __restrict__ cnt) {
  int e = blockIdx.x * 256 + threadIdx.x;
  if (e < Ne) atomicAdd(&cnt[dst[e]], 1);
}

__global__ __launch_bounds__(1024) void k_scan(const int* __restrict__ cnt,
                                               int* __restrict__ rowptr,
                                               int* __restrict__ cursor,
                                               float* __restrict__ dinv) {
  __shared__ int ssum[1024];
  const int t = threadIdx.x;
  const int CH = (Nn + 1023) / 1024;  // 49
  const int i0 = t * CH;
  const int i1 = min(i0 + CH, Nn);
  int s = 0;
  for (int i = i0; i < i1; ++i) s += cnt[i] + 1;  // +1 self loop
  ssum[t] = s;
  __syncthreads();
  for (int off = 1; off < 1024; off <<= 1) {
    int v = ssum[t];
    int u = (t >= off) ? ssum[t - off] : 0;
    __syncthreads();
    ssum[t] = v + u;
    __syncthreads();
  }
  int run = (t == 0) ? 0 : ssum[t - 1];
  for (int i = i0; i < i1; ++i) {
    int c = cnt[i] + 1;
    rowptr[i] = run;
    cursor[i] = run;
    dinv[i] = rsqrtf((float)c);
    run += c;
  }
  if (t == 1023) rowptr[Nn] = run;  // = Ne + Nn
}

__global__ void k_fill(const int* __restrict__ src, const int* __restrict__ dst,
                       const float* __restrict__ dinv, int* __restrict__ cursor,
                       int* __restrict__ csrs, float* __restrict__ csrn) {
  int e = blockIdx.x * 256 + threadIdx.x;
  if (e < Ne) {
    int s = src[e], d = dst[e];
    int pos = atomicAdd(&cursor[d], 1);
    csrs[pos] = s;
    csrn[pos] = dinv[s] * dinv[d];
  } else if (e < Ne + Nn) {
    int d = e - Ne;  // self loop
    int pos = atomicAdd(&cursor[d], 1);
    csrs[pos] = d;
    float v = dinv[d];
    csrn[pos] = v * v;
  }
}

// ---------------- weight transpose + bf16 cast: Wt[c][k] = W[k][c] ----------------
__global__ void k_wt(const float* __restrict__ W, unsigned short* __restrict__ Wt,
                     int K, int H, int Hpad) {
  int idx = blockIdx.x * 256 + threadIdx.x;
  if (idx >= Hpad * K) return;
  int c = idx / K, k = idx - c * K;
  float v = (c < H) ? W[(size_t)k * H + c] : 0.0f;
  Wt[idx] = f2bf(v);
}

// ---------------- GEMM: C[M x ncols] = A[M x K] @ W, bf16 MFMA ----------------
// MODE 0: A = bf16 row-major (lda elems)
// MODE 1: A(r,k) = feat[(k>>7)*Nn*Fd + r*Fd + (k&127)] * (ow ? ow[(k>>7)&1] : 1)  (f32 source)
template <int MODE>
__global__ __launch_bounds__(256) void k_gemm(
    const void* __restrict__ Aptr, int lda, int K,
    const unsigned short* __restrict__ Wt,  // [Hpad][K] bf16
    const float* __restrict__ ow, const float* __restrict__ bias,
    unsigned short* __restrict__ Cout, int ldc, int col_off, int ncols, int relu) {
  __shared__ short lA[128 * 64];
  __shared__ short lB[128 * 64];
  const int tid = threadIdx.x;
  const int lane = tid & 63;
  const int wid = tid >> 6;
  const int wr = wid >> 1, wc = wid & 1;
  const int row0 = blockIdx.x * 128;
  const int col0 = blockIdx.y * 128;

  f32x4 acc[4][4];
#pragma unroll
  for (int i = 0; i < 4; ++i)
#pragma unroll
    for (int j = 0; j < 4; ++j) acc[i][j] = (f32x4)0.0f;

  const int sr = tid >> 1;          // staging row (A) / col (B)
  const int sh = (tid & 1) * 32;    // k-half
  const s16x8 VZ = (s16x8)0;

  const int nkt = K >> 6;
  for (int kt = 0; kt < nkt; ++kt) {
    const int k0 = kt * 64;
    // ---- stage A tile (128 x 64 bf16), XOR-swizzled
    {
      const int row = row0 + sr;
      const bool rv = row < Nn;
      s16x8 v[4];
      if (MODE == 0) {
        const unsigned short* A = (const unsigned short*)Aptr;
        const s16x8* p = (const s16x8*)(A + (size_t)row * lda + k0 + sh);
#pragma unroll
        for (int j = 0; j < 4; ++j) v[j] = rv ? p[j] : VZ;
      } else {
        const float* feat = (const float*)Aptr;
        const int c = k0 >> 7;
        const int f0 = k0 & 127;
        const float scale = ow ? ow[c & 1] : 1.0f;
        const float* p = feat + (size_t)c * ((size_t)Nn * Fd) + (size_t)row * Fd + f0 + sh;
#pragma unroll
        for (int j = 0; j < 4; ++j) {
          f32x4 a = rv ? *(const f32x4*)(p + j * 8) : (f32x4)0.0f;
          f32x4 b = rv ? *(const f32x4*)(p + j * 8 + 4) : (f32x4)0.0f;
          s16x8 t;
#pragma unroll
          for (int q = 0; q < 4; ++q) t[q] = (short)f2bf(a[q] * scale);
#pragma unroll
          for (int q = 0; q < 4; ++q) t[4 + q] = (short)f2bf(b[q] * scale);
          v[j] = t;
        }
      }
#pragma unroll
      for (int j = 0; j < 4; ++j) {
        int byte = sr * 128 + sh * 2 + j * 16;
        byte ^= (sr & 7) << 4;
        *(s16x8*)((char*)lA + byte) = v[j];
      }
    }
    // ---- stage B tile (128 cols x 64 k bf16) from pre-transposed Wt
    {
      const s16x8* p = (const s16x8*)(Wt + (size_t)(col0 + sr) * K + k0 + sh);
#pragma unroll
      for (int j = 0; j < 4; ++j) {
        s16x8 v = p[j];
        int byte = sr * 128 + sh * 2 + j * 16;
        byte ^= (sr & 7) << 4;
        *(s16x8*)((char*)lB + byte) = v;
      }
    }
    __syncthreads();
    // ---- compute: 2 k-slices of 32, 4x4 frags per wave
#pragma unroll
    for (int kk = 0; kk < 2; ++kk) {
      s16x8 af[4], bv[4];
#pragma unroll
      for (int mi = 0; mi < 4; ++mi) {
        int r = wr * 64 + mi * 16 + (lane & 15);
        int byte = r * 128 + kk * 64 + (lane >> 4) * 16;
        byte ^= (r & 7) << 4;
        af[mi] = *(const s16x8*)((const char*)lA + byte);
      }
#pragma unroll
      for (int ni = 0; ni < 4; ++ni) {
        int c = wc * 64 + ni * 16 + (lane & 15);
        int byte = c * 128 + kk * 64 + (lane >> 4) * 16;
        byte ^= (c & 7) << 4;
        bv[ni] = *(const s16x8*)((const char*)lB + byte);
      }
#pragma unroll
      for (int mi = 0; mi < 4; ++mi)
#pragma unroll
        for (int ni = 0; ni < 4; ++ni)
          acc[mi][ni] = __builtin_amdgcn_mfma_f32_16x16x32_bf16(af[mi], bv[ni], acc[mi][ni], 0, 0, 0);
    }
    __syncthreads();
  }

  // ---- epilogue: bias / relu / bf16 store
#pragma unroll
  for (int ni = 0; ni < 4; ++ni) {
    const int col = col0 + wc * 64 + ni * 16 + (lane & 15);
    if (col >= ncols) continue;
    const float bvl = bias ? bias[col] : 0.0f;
#pragma unroll
    for (int mi = 0; mi < 4; ++mi) {
      const int rb = row0 + wr * 64 + mi * 16 + ((lane >> 4) << 2);
#pragma unroll
      for (int q = 0; q < 4; ++q) {
        int r = rb + q;
        if (r < Nn) {
          float vv = acc[mi][ni][q] + bvl;
          if (relu) vv = fmaxf(vv, 0.0f);
          Cout[(size_t)r * ldc + col_off + col] = f2bf(vv);
        }
      }
    }
  }
}

// ---------------- gather (aggregate) 256-dim: one wave per node ----------------
__global__ __launch_bounds__(256) void k_gather(
    const unsigned short* __restrict__ m, const int* __restrict__ rowptr,
    const int* __restrict__ csrs, const float* __restrict__ csrn,
    const float* __restrict__ bias, unsigned short* __restrict__ outp,
    int ldc, int col_off) {
  const int wid = (blockIdx.x * 256 + threadIdx.x) >> 6;
  const int lane = threadIdx.x & 63;
  if (wid >= Nn) return;
  const int e0 = rowptr[wid], e1 = rowptr[wid + 1];
  float a0 = 0.f, a1 = 0.f, a2 = 0.f, a3 = 0.f;
  for (int base = e0; base < e1; base += 64) {
    int idx = base + lane;
    int s_ = 0;
    float w_ = 0.f;
    if (idx < e1) { s_ = csrs[idx]; w_ = csrn[idx]; }
    const int cn = min(64, e1 - base);
    for (int j = 0; j < cn; ++j) {
      const int s = __shfl(s_, j);
      const float w = __shfl(w_, j);
      const ushort4 v = *(const ushort4*)(m + (size_t)s * Hd + lane * 4);
      a0 += w * bf2f(v.x);
      a1 += w * bf2f(v.y);
      a2 += w * bf2f(v.z);
      a3 += w * bf2f(v.w);
    }
  }
  a0 = fmaxf(a0 + bias[lane * 4 + 0], 0.f);
  a1 = fmaxf(a1 + bias[lane * 4 + 1], 0.f);
  a2 = fmaxf(a2 + bias[lane * 4 + 2], 0.f);
  a3 = fmaxf(a3 + bias[lane * 4 + 3], 0.f);
  ushort4 o;
  o.x = f2bf(a0); o.y = f2bf(a1); o.z = f2bf(a2); o.w = f2bf(a3);
  *(ushort4*)(outp + (size_t)wid * ldc + col_off + lane * 4) = o;
}

// ---------------- cls gather + bias + log_softmax (40 dims, lanes 0..9) ----------------
__global__ __launch_bounds__(256) void k_gcls(
    const unsigned short* __restrict__ mc, const int* __restrict__ rowptr,
    const int* __restrict__ csrs, const float* __restrict__ csrn,
    const float* __restrict__ clsb, float* __restrict__ outp) {
  const int wid = (blockIdx.x * 256 + threadIdx.x) >> 6;
  const int lane = threadIdx.x & 63;
  if (wid >= Nn) return;
  const bool act = lane < 10;
  const int e0 = rowptr[wid], e1 = rowptr[wid + 1];
  float a0 = 0.f, a1 = 0.f, a2 = 0.f, a3 = 0.f;
  for (int base = e0; base < e1; base += 64) {
    int idx = base + lane;
    int s_ = 0;
    float w_ = 0.f;
    if (idx < e1) { s_ = csrs[idx]; w_ = csrn[idx]; }
    const int cn = min(64, e1 - base);
    for (int j = 0; j < cn; ++j) {
      const int s = __shfl(s_, j);
      const float w = __shfl(w_, j);
      if (act) {
        const ushort4 v = *(const ushort4*)(mc + (size_t)s * Cd + lane * 4);
        a0 += w * bf2f(v.x);
        a1 += w * bf2f(v.y);
        a2 += w * bf2f(v.z);
        a3 += w * bf2f(v.w);
      }
    }
  }
  float l0 = 0.f, l1 = 0.f, l2 = 0.f, l3 = 0.f;
  if (act) {
    l0 = a0 + clsb[lane * 4 + 0];
    l1 = a1 + clsb[lane * 4 + 1];
    l2 = a2 + clsb[lane * 4 + 2];
    l3 = a3 + clsb[lane * 4 + 3];
  }
  float mx = act ? fmaxf(fmaxf(l0, l1), fmaxf(l2, l3)) : -3.4e38f;
#pragma unroll
  for (int off = 32; off; off >>= 1) mx = fmaxf(mx, __shfl_xor(mx, off));
  float se = act ? (expf(l0 - mx) + expf(l1 - mx) + expf(l2 - mx) + expf(l3 - mx)) : 0.f;
#pragma unroll
  for (int off = 32; off; off >>= 1) se += __shfl_xor(se, off);
  const float lse = mx + logf(se);
  if (act) {
    float* o1 = outp + (size_t)wid * Cd + lane * 4;
    float* o2 = outp + (size_t)Nn * Cd + (size_t)wid * Cd + lane * 4;
    o1[0] = l0 - lse; o1[1] = l1 - lse; o1[2] = l2 - lse; o1[3] = l3 - lse;
    o2[0] = l0; o2[1] = l1; o2[2] = l2; o2[3] = l3;
  }
}

}  // namespace

extern "C" void kernel_launch(void* const* d_in, const int* in_sizes, int n_in,
                              void* d_out, int out_size, void* d_ws, size_t ws_size,
                              hipStream_t stream) {
  (void)in_sizes; (void)n_in; (void)out_size; (void)ws_size;
  const float* x       = (const float*)d_in[0];
  const float* feature = (const float*)d_in[1];
  const int* src       = (const int*)d_in[2];
  const int* dst       = (const int*)d_in[3];
  const float* convW[3] = {(const float*)d_in[4], (const float*)d_in[6], (const float*)d_in[8]};
  const float* convB[3] = {(const float*)d_in[5], (const float*)d_in[7], (const float*)d_in[9]};
  const float* linW[3]  = {(const float*)d_in[10], (const float*)d_in[12], (const float*)d_in[14]};
  const float* linB[3]  = {(const float*)d_in[11], (const float*)d_in[13], (const float*)d_in[15]};
  const float* oweights = (const float*)d_in[16];
  const float* clsW     = (const float*)d_in[17];
  const float* clsB     = (const float*)d_in[18];
  float* out = (float*)d_out;

  char* wsp = (char*)d_ws;
  auto alloc = [&](size_t bytes) -> void* {
    void* p = wsp;
    wsp += (bytes + 255) & ~(size_t)255;
    return p;
  };
  int* cnt      = (int*)alloc((size_t)Nn * 4);
  int* cursor   = (int*)alloc((size_t)Nn * 4);
  int* rowptr   = (int*)alloc((size_t)(Nn + 1) * 4);
  float* dinv   = (float*)alloc((size_t)Nn * 4);
  int* csrs     = (int*)alloc((size_t)(Ne + Nn) * 4);
  float* csrn   = (float*)alloc((size_t)(Ne + Nn) * 4);
  unsigned short* WtC0 = (unsigned short*)alloc((size_t)256 * 128 * 2);
  unsigned short* WtC1 = (unsigned short*)alloc((size_t)256 * 512 * 2);
  unsigned short* WtC2 = (unsigned short*)alloc((size_t)256 * 512 * 2);
  unsigned short* WtL0 = (unsigned short*)alloc((size_t)256 * 128 * 2);
  unsigned short* WtL1 = (unsigned short*)alloc((size_t)256 * 256 * 2);
  unsigned short* WtL2 = (unsigned short*)alloc((size_t)256 * 512 * 2);
  unsigned short* WtCl = (unsigned short*)alloc((size_t)128 * 512 * 2);
  unsigned short* mbuf = (unsigned short*)alloc((size_t)Nn * Hd * 2);
  unsigned short* mcls = (unsigned short*)alloc((size_t)Nn * Cd * 2);
  unsigned short* comb = (unsigned short*)alloc((size_t)Nn * 512 * 2);

  // ---- CSR build (per-call; deterministic up to fp addition order)
  k_zero<<<(Nn + 255) / 256, 256, 0, stream>>>(cnt);
  k_count<<<(Ne + 255) / 256, 256, 0, stream>>>(dst, cnt);
  k_scan<<<1, 1024, 0, stream>>>(cnt, rowptr, cursor, dinv);
  k_fill<<<(Ne + Nn + 255) / 256, 256, 0, stream>>>(src, dst, dinv, cursor, csrs, csrn);

  // ---- weights: transpose + bf16
  auto wt = [&](const float* W, unsigned short* Wt, int K, int H, int Hpad) {
    k_wt<<<(Hpad * K + 255) / 256, 256, 0, stream>>>(W, Wt, K, H, Hpad);
  };
  wt(convW[0], WtC0, 128, 256, 256);
  wt(convW[1], WtC1, 512, 256, 256);
  wt(convW[2], WtC2, 512, 256, 256);
  wt(linW[0], WtL0, 128, 256, 256);
  wt(linW[1], WtL1, 256, 256, 256);
  wt(linW[2], WtL2, 512, 256, 256);
  wt(clsW, WtCl, 512, 40, 128);

  const dim3 g2(391, 2), g1(391, 1);
  const int GB = (Nn * 64) / 256;  // 12500 blocks, one wave per node

  // ---- layer 0
  k_gemm<1><<<g2, 256, 0, stream>>>(x, 0, 128, WtC0, nullptr, nullptr, mbuf, Hd, 0, 256, 0);
  k_gemm<1><<<g2, 256, 0, stream>>>(feature, 0, 128, WtL0, nullptr, linB[0], comb, 512, 0, 256, 1);
  k_gather<<<GB, 256, 0, stream>>>(mbuf, rowptr, csrs, csrn, convB[0], comb, 512, 256);
  // ---- layer 1
  k_gemm<0><<<g2, 256, 0, stream>>>(comb, 512, 512, WtC1, nullptr, nullptr, mbuf, Hd, 0, 256, 0);
  k_gemm<1><<<g2, 256, 0, stream>>>(feature + (size_t)1 * Nn * Fd, 0, 256, WtL1, oweights, linB[1], comb, 512, 0, 256, 1);
  k_gather<<<GB, 256, 0, stream>>>(mbuf, rowptr, csrs, csrn, convB[1], comb, 512, 256);
  // ---- layer 2
  k_gemm<0><<<g2, 256, 0, stream>>>(comb, 512, 512, WtC2, nullptr, nullptr, mbuf, Hd, 0, 256, 0);
  k_gemm<1><<<g2, 256, 0, stream>>>(feature + (size_t)3 * Nn * Fd, 0, 512, WtL2, oweights, linB[2], comb, 512, 0, 256, 1);
  k_gather<<<GB, 256, 0, stream>>>(mbuf, rowptr, csrs, csrn, convB[2], comb, 512, 256);
  // ---- classifier
  k_gemm<0><<<g1, 256, 0, stream>>>(comb, 512, 512, WtCl, nullptr, nullptr, mcls, Cd, 0, 40, 0);
  k_gcls<<<GB, 256, 0, stream>>>(mcls, rowptr, csrs, csrn, clsB, out);
}

// Round 2
// 702.280 us; speedup vs baseline: 1.1698x; 1.1698x over previous
//
#include <hip/hip_runtime.h>

#define DEVI __device__ __forceinline__

namespace {

constexpr int Nn = 50000;   // nodes
constexpr int Ne = 800000;  // edges
constexpr int Fd = 128;     // feature dim
constexpr int Hd = 256;     // hidden
constexpr int Cd = 40;      // classes
constexpr int NB = (Nn + 255) / 256;  // 196 scan blocks

typedef __attribute__((ext_vector_type(8))) short s16x8;   // 8 bf16 (4 VGPR) MFMA frag
typedef __attribute__((ext_vector_type(4))) float f32x4;

DEVI unsigned short f2bf(float f) {
  unsigned int u = __builtin_bit_cast(unsigned int, f);
  u += 0x7fffu + ((u >> 16) & 1u);   // RNE
  return (unsigned short)(u >> 16);
}
DEVI float bf2f(unsigned short s) {
  return __builtin_bit_cast(float, ((unsigned int)s) << 16);
}

// ---------------- CSR build ----------------
__global__ void k_zero(int* cnt) {
  int i = blockIdx.x * 256 + threadIdx.x;
  if (i < Nn) cnt[i] = 0;
}

__global__ void k_count(const int* __restrict__ dst, int* __restrict__ cnt) {
  int e = blockIdx.x * 256 + threadIdx.x;
  if (e < Ne) atomicAdd(&cnt[dst[e]], 1);
}

// level 1: per-block sums of (cnt[i]+1)
__global__ __launch_bounds__(256) void k_partial(const int* __restrict__ cnt,
                                                 int* __restrict__ partial) {
  __shared__ int red[256];
  const int t = threadIdx.x;
  const int i = blockIdx.x * 256 + t;
  red[t] = (i < Nn) ? cnt[i] + 1 : 0;
  __syncthreads();
#pragma unroll
  for (int off = 128; off; off >>= 1) {
    if (t < off) red[t] += red[t + off];
    __syncthreads();
  }
  if (t == 0) partial[blockIdx.x] = red[0];
}

// level 2: scan the 196 partials (tiny, one block)
__global__ __launch_bounds__(256) void k_scan_small(const int* __restrict__ partial,
                                                    int* __restrict__ poffs,
                                                    int* __restrict__ rowptr) {
  __shared__ int s[256];
  const int t = threadIdx.x;
  const int v = (t < NB) ? partial[t] : 0;
  s[t] = v;
  __syncthreads();
#pragma unroll
  for (int off = 1; off < 256; off <<= 1) {
    int add = (t >= off) ? s[t - off] : 0;
    __syncthreads();
    s[t] += add;
    __syncthreads();
  }
  if (t < NB) poffs[t] = s[t] - v;        // exclusive
  if (t == NB - 1) rowptr[Nn] = s[t];     // total = Ne + Nn
}

// level 3: per-block scan + offset -> rowptr / cursor / dinv
__global__ __launch_bounds__(256) void k_rowptr(const int* __restrict__ cnt,
                                                const int* __restrict__ poffs,
                                                int* __restrict__ rowptr,
                                                int* __restrict__ cursor,
                                                float* __restrict__ dinv) {
  __shared__ int s[256];
  const int t = threadIdx.x;
  const int i = blockIdx.x * 256 + t;
  const int c = (i < Nn) ? cnt[i] + 1 : 0;
  s[t] = c;
  __syncthreads();
#pragma unroll
  for (int off = 1; off < 256; off <<= 1) {
    int add = (t >= off) ? s[t - off] : 0;
    __syncthreads();
    s[t] += add;
    __syncthreads();
  }
  if (i < Nn) {
    const int excl = s[t] - c + poffs[blockIdx.x];
    rowptr[i] = excl;
    cursor[i] = excl;
    dinv[i] = rsqrtf((float)c);
  }
}

__global__ void k_fill(const int* __restrict__ src, const int* __restrict__ dst,
                       const float* __restrict__ dinv, int* __restrict__ cursor,
                       int* __restrict__ csrs, float* __restrict__ csrn) {
  int e = blockIdx.x * 256 + threadIdx.x;
  if (e < Ne) {
    int s = src[e], d = dst[e];
    int pos = atomicAdd(&cursor[d], 1);
    csrs[pos] = s;
    csrn[pos] = dinv[s] * dinv[d];
  } else if (e < Ne + Nn) {
    int d = e - Ne;  // self loop
    int pos = atomicAdd(&cursor[d], 1);
    csrs[pos] = d;
    float v = dinv[d];
    csrn[pos] = v * v;
  }
}

// ---------------- weight transpose + bf16 cast: Wt[c][k] = W[k][c] ----------------
__global__ void k_wt(const float* __restrict__ W, unsigned short* __restrict__ Wt,
                     int K, int H, int Hpad) {
  int idx = blockIdx.x * 256 + threadIdx.x;
  if (idx >= Hpad * K) return;
  int c = idx / K, k = idx - c * K;
  float v = (c < H) ? W[(size_t)k * H + c] : 0.0f;
  Wt[idx] = f2bf(v);
}

// ---------------- GEMM: C[M x ncols] = A[M x K] @ W, bf16 MFMA ----------------
// MODE 0: A = bf16 row-major (lda elems)
// MODE 1: A(r,k) = feat[(k>>7)*Nn*Fd + r*Fd + (k&127)] * (ow ? ow[(k>>7)&1] : 1)  (f32 source)
template <int MODE>
__global__ __launch_bounds__(256) void k_gemm(
    const void* __restrict__ Aptr, int lda, int K,
    const unsigned short* __restrict__ Wt,  // [Hpad][K] bf16
    const float* __restrict__ ow, const float* __restrict__ bias,
    unsigned short* __restrict__ Cout, int ldc, int col_off, int ncols, int relu) {
  __shared__ short lA[128 * 64];
  __shared__ short lB[128 * 64];
  const int tid = threadIdx.x;
  const int lane = tid & 63;
  const int wid = tid >> 6;
  const int wr = wid >> 1, wc = wid & 1;
  const int row0 = blockIdx.x * 128;
  const int col0 = blockIdx.y * 128;

  f32x4 acc[4][4];
#pragma unroll
  for (int i = 0; i < 4; ++i)
#pragma unroll
    for (int j = 0; j < 4; ++j) acc[i][j] = (f32x4)0.0f;

  const int sr = tid >> 1;          // staging row (A) / col (B)
  const int sh = (tid & 1) * 32;    // k-half
  const s16x8 VZ = (s16x8)0;

  const int nkt = K >> 6;
  for (int kt = 0; kt < nkt; ++kt) {
    const int k0 = kt * 64;
    // ---- stage A tile (128 x 64 bf16), XOR-swizzled
    {
      const int row = row0 + sr;
      const bool rv = row < Nn;
      s16x8 v[4];
      if (MODE == 0) {
        const unsigned short* A = (const unsigned short*)Aptr;
        const s16x8* p = (const s16x8*)(A + (size_t)row * lda + k0 + sh);
#pragma unroll
        for (int j = 0; j < 4; ++j) v[j] = rv ? p[j] : VZ;
      } else {
        const float* feat = (const float*)Aptr;
        const int c = k0 >> 7;
        const int f0 = k0 & 127;
        const float scale = ow ? ow[c & 1] : 1.0f;
        const float* p = feat + (size_t)c * ((size_t)Nn * Fd) + (size_t)row * Fd + f0 + sh;
#pragma unroll
        for (int j = 0; j < 4; ++j) {
          f32x4 a = rv ? *(const f32x4*)(p + j * 8) : (f32x4)0.0f;
          f32x4 b = rv ? *(const f32x4*)(p + j * 8 + 4) : (f32x4)0.0f;
          s16x8 t;
#pragma unroll
          for (int q = 0; q < 4; ++q) t[q] = (short)f2bf(a[q] * scale);
#pragma unroll
          for (int q = 0; q < 4; ++q) t[4 + q] = (short)f2bf(b[q] * scale);
          v[j] = t;
        }
      }
#pragma unroll
      for (int j = 0; j < 4; ++j) {
        int byte = sr * 128 + sh * 2 + j * 16;
        byte ^= (sr & 7) << 4;
        *(s16x8*)((char*)lA + byte) = v[j];
      }
    }
    // ---- stage B tile (128 cols x 64 k bf16) from pre-transposed Wt
    {
      const s16x8* p = (const s16x8*)(Wt + (size_t)(col0 + sr) * K + k0 + sh);
#pragma unroll
      for (int j = 0; j < 4; ++j) {
        s16x8 v = p[j];
        int byte = sr * 128 + sh * 2 + j * 16;
        byte ^= (sr & 7) << 4;
        *(s16x8*)((char*)lB + byte) = v;
      }
    }
    __syncthreads();
    // ---- compute: 2 k-slices of 32, 4x4 frags per wave
#pragma unroll
    for (int kk = 0; kk < 2; ++kk) {
      s16x8 af[4], bv[4];
#pragma unroll
      for (int mi = 0; mi < 4; ++mi) {
        int r = wr * 64 + mi * 16 + (lane & 15);
        int byte = r * 128 + kk * 64 + (lane >> 4) * 16;
        byte ^= (r & 7) << 4;
        af[mi] = *(const s16x8*)((const char*)lA + byte);
      }
#pragma unroll
      for (int ni = 0; ni < 4; ++ni) {
        int c = wc * 64 + ni * 16 + (lane & 15);
        int byte = c * 128 + kk * 64 + (lane >> 4) * 16;
        byte ^= (c & 7) << 4;
        bv[ni] = *(const s16x8*)((const char*)lB + byte);
      }
#pragma unroll
      for (int mi = 0; mi < 4; ++mi)
#pragma unroll
        for (int ni = 0; ni < 4; ++ni)
          acc[mi][ni] = __builtin_amdgcn_mfma_f32_16x16x32_bf16(af[mi], bv[ni], acc[mi][ni], 0, 0, 0);
    }
    __syncthreads();
  }

  // ---- epilogue: bias / relu / bf16 store
#pragma unroll
  for (int ni = 0; ni < 4; ++ni) {
    const int col = col0 + wc * 64 + ni * 16 + (lane & 15);
    if (col >= ncols) continue;
    const float bvl = bias ? bias[col] : 0.0f;
#pragma unroll
    for (int mi = 0; mi < 4; ++mi) {
      const int rb = row0 + wr * 64 + mi * 16 + ((lane >> 4) << 2);
#pragma unroll
      for (int q = 0; q < 4; ++q) {
        int r = rb + q;
        if (r < Nn) {
          float vv = acc[mi][ni][q] + bvl;
          if (relu) vv = fmaxf(vv, 0.0f);
          Cout[(size_t)r * ldc + col_off + col] = f2bf(vv);
        }
      }
    }
  }
}

// ---------------- gather (aggregate) 256-dim: one wave per node ----------------
__global__ __launch_bounds__(256) void k_gather(
    const unsigned short* __restrict__ m, const int* __restrict__ rowptr,
    const int* __restrict__ csrs, const float* __restrict__ csrn,
    const float* __restrict__ bias, unsigned short* __restrict__ outp,
    int ldc, int col_off) {
  const int wid = (blockIdx.x * 256 + threadIdx.x) >> 6;
  const int lane = threadIdx.x & 63;
  if (wid >= Nn) return;
  const int e0 = rowptr[wid], e1 = rowptr[wid + 1];
  float a0 = 0.f, a1 = 0.f, a2 = 0.f, a3 = 0.f;
  for (int base = e0; base < e1; base += 64) {
    int idx = base + lane;
    int s_ = 0;
    float w_ = 0.f;
    if (idx < e1) { s_ = csrs[idx]; w_ = csrn[idx]; }
    const int cn = min(64, e1 - base);
    for (int j = 0; j < cn; ++j) {
      const int s = __shfl(s_, j);
      const float w = __shfl(w_, j);
      const ushort4 v = *(const ushort4*)(m + (size_t)s * Hd + lane * 4);
      a0 += w * bf2f(v.x);
      a1 += w * bf2f(v.y);
      a2 += w * bf2f(v.z);
      a3 += w * bf2f(v.w);
    }
  }
  a0 = fmaxf(a0 + bias[lane * 4 + 0], 0.f);
  a1 = fmaxf(a1 + bias[lane * 4 + 1], 0.f);
  a2 = fmaxf(a2 + bias[lane * 4 + 2], 0.f);
  a3 = fmaxf(a3 + bias[lane * 4 + 3], 0.f);
  ushort4 o;
  o.x = f2bf(a0); o.y = f2bf(a1); o.z = f2bf(a2); o.w = f2bf(a3);
  *(ushort4*)(outp + (size_t)wid * ldc + col_off + lane * 4) = o;
}

// ---------------- cls gather + bias + log_softmax (40 dims, lanes 0..9) ----------------
__global__ __launch_bounds__(256) void k_gcls(
    const unsigned short* __restrict__ mc, const int* __restrict__ rowptr,
    const int* __restrict__ csrs, const float* __restrict__ csrn,
    const float* __restrict__ clsb, float* __restrict__ outp) {
  const int wid = (blockIdx.x * 256 + threadIdx.x) >> 6;
  const int lane = threadIdx.x & 63;
  if (wid >= Nn) return;
  const bool act = lane < 10;
  const int e0 = rowptr[wid], e1 = rowptr[wid + 1];
  float a0 = 0.f, a1 = 0.f, a2 = 0.f, a3 = 0.f;
  for (int base = e0; base < e1; base += 64) {
    int idx = base + lane;
    int s_ = 0;
    float w_ = 0.f;
    if (idx < e1) { s_ = csrs[idx]; w_ = csrn[idx]; }
    const int cn = min(64, e1 - base);
    for (int j = 0; j < cn; ++j) {
      const int s = __shfl(s_, j);
      const float w = __shfl(w_, j);
      if (act) {
        const ushort4 v = *(const ushort4*)(mc + (size_t)s * Cd + lane * 4);
        a0 += w * bf2f(v.x);
        a1 += w * bf2f(v.y);
        a2 += w * bf2f(v.z);
        a3 += w * bf2f(v.w);
      }
    }
  }
  float l0 = 0.f, l1 = 0.f, l2 = 0.f, l3 = 0.f;
  if (act) {
    l0 = a0 + clsb[lane * 4 + 0];
    l1 = a1 + clsb[lane * 4 + 1];
    l2 = a2 + clsb[lane * 4 + 2];
    l3 = a3 + clsb[lane * 4 + 3];
  }
  float mx = act ? fmaxf(fmaxf(l0, l1), fmaxf(l2, l3)) : -3.4e38f;
#pragma unroll
  for (int off = 32; off; off >>= 1) mx = fmaxf(mx, __shfl_xor(mx, off));
  float se = act ? (expf(l0 - mx) + expf(l1 - mx) + expf(l2 - mx) + expf(l3 - mx)) : 0.f;
#pragma unroll
  for (int off = 32; off; off >>= 1) se += __shfl_xor(se, off);
  const float lse = mx + logf(se);
  if (act) {
    float* o1 = outp + (size_t)wid * Cd + lane * 4;
    float* o2 = outp + (size_t)Nn * Cd + (size_t)wid * Cd + lane * 4;
    o1[0] = l0 - lse; o1[1] = l1 - lse; o1[2] = l2 - lse; o1[3] = l3 - lse;
    o2[0] = l0; o2[1] = l1; o2[2] = l2; o2[3] = l3;
  }
}

}  // namespace

extern "C" void kernel_launch(void* const* d_in, const int* in_sizes, int n_in,
                              void* d_out, int out_size, void* d_ws, size_t ws_size,
                              hipStream_t stream) {
  (void)in_sizes; (void)n_in; (void)out_size; (void)ws_size;
  const float* x       = (const float*)d_in[0];
  const float* feature = (const float*)d_in[1];
  const int* src       = (const int*)d_in[2];
  const int* dst       = (const int*)d_in[3];
  const float* convW[3] = {(const float*)d_in[4], (const float*)d_in[6], (const float*)d_in[8]};
  const float* convB[3] = {(const float*)d_in[5], (const float*)d_in[7], (const float*)d_in[9]};
  const float* linW[3]  = {(const float*)d_in[10], (const float*)d_in[12], (const float*)d_in[14]};
  const float* linB[3]  = {(const float*)d_in[11], (const float*)d_in[13], (const float*)d_in[15]};
  const float* oweights = (const float*)d_in[16];
  const float* clsW     = (const float*)d_in[17];
  const float* clsB     = (const float*)d_in[18];
  float* out = (float*)d_out;

  char* wsp = (char*)d_ws;
  auto alloc = [&](size_t bytes) -> void* {
    void* p = wsp;
    wsp += (bytes + 255) & ~(size_t)255;
    return p;
  };
  int* cnt      = (int*)alloc((size_t)Nn * 4);
  int* cursor   = (int*)alloc((size_t)Nn * 4);
  int* rowptr   = (int*)alloc((size_t)(Nn + 1) * 4);
  float* dinv   = (float*)alloc((size_t)Nn * 4);
  int* partial  = (int*)alloc((size_t)NB * 4);
  int* poffs    = (int*)alloc((size_t)NB * 4);
  int* csrs     = (int*)alloc((size_t)(Ne + Nn) * 4);
  float* csrn   = (float*)alloc((size_t)(Ne + Nn) * 4);
  unsigned short* WtC0 = (unsigned short*)alloc((size_t)256 * 128 * 2);
  unsigned short* WtC1 = (unsigned short*)alloc((size_t)256 * 512 * 2);
  unsigned short* WtC2 = (unsigned short*)alloc((size_t)256 * 512 * 2);
  unsigned short* WtL0 = (unsigned short*)alloc((size_t)256 * 128 * 2);
  unsigned short* WtL1 = (unsigned short*)alloc((size_t)256 * 256 * 2);
  unsigned short* WtL2 = (unsigned short*)alloc((size_t)256 * 512 * 2);
  unsigned short* WtCl = (unsigned short*)alloc((size_t)128 * 512 * 2);
  unsigned short* mbuf = (unsigned short*)alloc((size_t)Nn * Hd * 2);
  unsigned short* mcls = (unsigned short*)alloc((size_t)Nn * Cd * 2);
  unsigned short* comb = (unsigned short*)alloc((size_t)Nn * 512 * 2);

  // ---- CSR build (3-level parallel scan instead of single-block scan)
  k_zero<<<(Nn + 255) / 256, 256, 0, stream>>>(cnt);
  k_count<<<(Ne + 255) / 256, 256, 0, stream>>>(dst, cnt);
  k_partial<<<NB, 256, 0, stream>>>(cnt, partial);
  k_scan_small<<<1, 256, 0, stream>>>(partial, poffs, rowptr);
  k_rowptr<<<NB, 256, 0, stream>>>(cnt, poffs, rowptr, cursor, dinv);
  k_fill<<<(Ne + Nn + 255) / 256, 256, 0, stream>>>(src, dst, dinv, cursor, csrs, csrn);

  // ---- weights: transpose + bf16
  auto wt = [&](const float* W, unsigned short* Wt, int K, int H, int Hpad) {
    k_wt<<<(Hpad * K + 255) / 256, 256, 0, stream>>>(W, Wt, K, H, Hpad);
  };
  wt(convW[0], WtC0, 128, 256, 256);
  wt(convW[1], WtC1, 512, 256, 256);
  wt(convW[2], WtC2, 512, 256, 256);
  wt(linW[0], WtL0, 128, 256, 256);
  wt(linW[1], WtL1, 256, 256, 256);
  wt(linW[2], WtL2, 512, 256, 256);
  wt(clsW, WtCl, 512, 40, 128);

  const dim3 g2(391, 2), g1(391, 1);
  const int GB = (Nn * 64) / 256;  // 12500 blocks, one wave per node

  // ---- layer 0
  k_gemm<1><<<g2, 256, 0, stream>>>(x, 0, 128, WtC0, nullptr, nullptr, mbuf, Hd, 0, 256, 0);
  k_gemm<1><<<g2, 256, 0, stream>>>(feature, 0, 128, WtL0, nullptr, linB[0], comb, 512, 0, 256, 1);
  k_gather<<<GB, 256, 0, stream>>>(mbuf, rowptr, csrs, csrn, convB[0], comb, 512, 256);
  // ---- layer 1
  k_gemm<0><<<g2, 256, 0, stream>>>(comb, 512, 512, WtC1, nullptr, nullptr, mbuf, Hd, 0, 256, 0);
  k_gemm<1><<<g2, 256, 0, stream>>>(feature + (size_t)1 * Nn * Fd, 0, 256, WtL1, oweights, linB[1], comb, 512, 0, 256, 1);
  k_gather<<<GB, 256, 0, stream>>>(mbuf, rowptr, csrs, csrn, convB[1], comb, 512, 256);
  // ---- layer 2
  k_gemm<0><<<g2, 256, 0, stream>>>(comb, 512, 512, WtC2, nullptr, nullptr, mbuf, Hd, 0, 256, 0);
  k_gemm<1><<<g2, 256, 0, stream>>>(feature + (size_t)3 * Nn * Fd, 0, 512, WtL2, oweights, linB[2], comb, 512, 0, 256, 1);
  k_gather<<<GB, 256, 0, stream>>>(mbuf, rowptr, csrs, csrn, convB[2], comb, 512, 256);
  // ---- classifier
  k_gemm<0><<<g1, 256, 0, stream>>>(comb, 512, 512, WtCl, nullptr, nullptr, mcls, Cd, 0, 40, 0);
  k_gcls<<<GB, 256, 0, stream>>>(mcls, rowptr, csrs, csrn, clsB, out);
}